// Round 5
// baseline (131.943 us; speedup 1.0000x reference)
//
#include <hip/hip_runtime.h>

typedef __bf16 bf16;
typedef __bf16 bf16x8 __attribute__((ext_vector_type(8)));
typedef __bf16 bf16x4 __attribute__((ext_vector_type(4)));
typedef float f32x4 __attribute__((ext_vector_type(4)));
typedef unsigned int u32;

#define NM 26

__device__ __forceinline__ bf16x8 splat8(u32 p) {
  union { u32 u[4]; bf16x8 v; } s;
  s.u[0] = p; s.u[1] = p; s.u[2] = p; s.u[3] = p;
  return s.v;
}

__device__ __forceinline__ u32 dup16(float v) {
  union { bf16 h; unsigned short s; } cv; cv.h = (bf16)v;
  return (u32)cv.s * 0x10001u;
}

// cin1G K-chunk step: sc + B-frag (LDS) prefetched 1 ahead; compute chunk J.
#define STEP(CUR, NXT, J) do {                                                 \
  { int jn = ((J)+1 > 25) ? 25 : (J)+1;                                        \
    sc[NXT][0] = dup16(spw[jn*32]);                                            \
    sc[NXT][1] = dup16(spw[jn*32 + 16]); }                                     \
  _Pragma("unroll")                                                            \
  for (int ni = 0; ni < 2; ++ni)                                               \
    Bf[NXT][ni] = *(const bf16x8*)&ldsB[((J)+1)*1024 + ni*512 + fo];           \
  _Pragma("unroll")                                                            \
  for (int mi = 0; mi < 2; ++mi) {                                             \
    bf16x8 af = xf[mi] * splat8(sc[CUR][mi]);                                  \
    _Pragma("unroll")                                                          \
    for (int ni = 0; ni < 2; ++ni)                                             \
      acc[mi][ni] = __builtin_amdgcn_mfma_f32_16x16x32_bf16(af, Bf[CUR][ni],   \
                                                            acc[mi][ni], 0, 0, 0); \
  }                                                                            \
} while (0)

// ---------------- cin1G: self-prep W1 quarter + layer 1 + fused G ------------
// Block = 256 thr (4 waves = 4 batches) x one h-quarter [h0, h0+32).
// Self-prep: W1[h0:h0+32] f32 -> frag-linear LDS tiles (26 chunks x 32x32,
// elem (hl, i) of chunk c at c*1024 + (hl>>4)*512 + (i>>3)*128 + (hl&15)*8
// + (i&7)); chunk 26 zeroed for the unconditional prefetch.
// XCD mapping: bid%8 == ms%8 (ms = batch/32 group) matches gemm2's G2 reads.
__global__ __launch_bounds__(256, 2) void cin1G(
    const float* __restrict__ in, const float* __restrict__ W1,
    const float* __restrict__ b1, bf16* __restrict__ G2, float* __restrict__ out)
{
  __shared__ __align__(16) bf16 ldsB[27*1024];    // 55,296 B
  __shared__ __align__(16) bf16 ldsT[4][32*36];   // 9,216 B (wave-private x1^T)
  const int t = threadIdx.x, bid = blockIdx.x;
  const int lane = t & 63, w = t >> 6;
  const int lr = lane & 15, lq = lane >> 4;
  const int fo = lq*128 + lr*8;
  // bid decode: ms (M32 group, ms%8 == bid%8), sub (batch sub-group), qq (h-quarter)
  const int x = bid & 7, mid = (bid >> 3) & 31, hi = bid >> 8;
  const int ms = hi*8 + x, sub = mid >> 2, qq = mid & 3;
  const int h0 = qq*32;
  const int bw = (ms*8 + sub)*4 + w;              // this wave's batch

  // ---- self-prep W1 quarter -> LDS (tasks = (hl, i), 4 rounds) ----
  #pragma unroll
  for (int r = 0; r < 4; ++r) {
    int task = r*256 + t;
    int hl = task >> 5, i = task & 31;
    const float* srcr = W1 + (h0 + hl)*(NM*NM) + i*NM;
    int dstb = (hl >> 4)*512 + (i >> 3)*128 + (hl & 15)*8 + (i & 7);
    if (i < NM) {
      #pragma unroll
      for (int c = 0; c < NM; ++c) ldsB[c*1024 + dstb] = (bf16)srcr[c];
    } else {
      #pragma unroll
      for (int c = 0; c < NM; ++c) ldsB[c*1024 + dstb] = (bf16)0.f;
    }
  }
  { bf16x4 z4; z4[0] = z4[1] = z4[2] = z4[3] = (bf16)0.f;
    *(bf16x4*)&ldsB[26*1024 + t*4] = z4; }        // zero pad chunk 26
  __syncthreads();

  const float* bin = in + (long)bw*(NM*32);
  const float* spw = bin + lr;                    // + j*32 + mi*16 (k = mi*16+lr)

  // x0 A-frags direct from in: xf[mi][e] = x0[bw][j=lq*8+e][k=mi*16+lr]
  bf16x8 xf[2];
  #pragma unroll
  for (int mi = 0; mi < 2; ++mi)
    #pragma unroll
    for (int e = 0; e < 8; ++e) {
      int j = lq*8 + e;
      xf[mi][e] = (bf16)((j < NM) ? bin[j*32 + mi*16 + lr] : 0.f);
    }

  f32x4 acc[2][2];
  #pragma unroll
  for (int mi=0; mi<2; ++mi)
    #pragma unroll
    for (int ni=0; ni<2; ++ni) acc[mi][ni] = {0.f,0.f,0.f,0.f};

  u32 sc[2][2];
  bf16x8 Bf[2][2];
  #pragma unroll
  for (int ni = 0; ni < 2; ++ni)
    Bf[0][ni] = *(const bf16x8*)&ldsB[ni*512 + fo];   // chunk 0
  sc[0][0] = dup16(spw[0]);  sc[0][1] = dup16(spw[16]);

  for (int jj = 0; jj < 13; ++jj) {
    STEP(0, 1, 2*jj);
    STEP(1, 0, 2*jj + 1);
  }

  float bias[2];
  #pragma unroll
  for (int ni=0; ni<2; ++ni) bias[ni] = b1[h0 + ni*16 + lr];

  // out[bw][h0:h0+32] = k-sum of x1 + 32*bias
  #pragma unroll
  for (int ni=0; ni<2; ++ni) {
    float vv = 0.f;
    #pragma unroll
    for (int mi=0; mi<2; ++mi)
      #pragma unroll
      for (int r=0; r<4; ++r) vv += acc[mi][ni][r];
    vv += __shfl_xor(vv, 16, 64);
    vv += __shfl_xor(vv, 32, 64);
    if (lq == 0) out[bw*256 + h0 + ni*16 + lr] = vv + 32.0f * bias[ni];
  }

  // x1 (C-layout) -> wave-private LDS [i_local][k], row stride 36
  bf16* T = &ldsT[w][0];
  #pragma unroll
  for (int mi=0; mi<2; ++mi)
    #pragma unroll
    for (int ni=0; ni<2; ++ni) {
      bf16x4 pk;
      #pragma unroll
      for (int r=0; r<4; ++r) pk[r] = (bf16)(acc[mi][ni][r] + bias[ni]);
      *(bf16x4*)&T[(ni*16+lr)*36 + mi*16 + lq*4] = pk;
    }
  // no barrier: each wave reads only its own tile (lgkmcnt ordering)

  // B-frags: x0[j][k] from in
  bf16x8 bg[2];
  #pragma unroll
  for (int nt = 0; nt < 2; ++nt) {
    int j = nt*16 + lr;
    bf16x8 vv;
    #pragma unroll
    for (int e=0; e<8; ++e) vv[e] = (bf16)0.f;
    if (j < NM) {
      const float* src = bin + j*32 + lq*8;
      f32x4 a = *(const f32x4*)src, c = *(const f32x4*)(src+4);
      #pragma unroll
      for (int e=0; e<4; ++e) { vv[e] = (bf16)a[e]; vv[4+e] = (bf16)c[e]; }
    }
    bg[nt] = vv;
  }
  // swapped G-MFMAs + vectorized tiled G2 stores (i range = this quarter)
  const long gbase = (long)(bw >> 5)*131072 + (bw & 31)*8;
  #pragma unroll
  for (int mt = 0; mt < 2; ++mt) {
    bf16x8 ag = *(const bf16x8*)&T[(mt*16+lr)*36 + lq*8];
    #pragma unroll
    for (int nt = 0; nt < 2; ++nt) {
      f32x4 z = {0.f,0.f,0.f,0.f};
      f32x4 g = __builtin_amdgcn_mfma_f32_16x16x32_bf16(bg[nt], ag, z, 0, 0, 0);
      // lane holds G[bw][i=h0+mt*16+lr][j=nt*16+lq*4+r]
      bf16x4 pk;
      #pragma unroll
      for (int r = 0; r < 4; ++r) pk[r] = (bf16)g[r];
      const int kh = (h0 + mt*16 + lr)*4 + nt*2 + (lq >> 1);
      *(bf16x4*)&G2[gbase + (long)kh*256 + (lq & 1)*4] = pk;
    }
  }
}

// ---------------- gemm2: out[b][128+h] += sum_K G[b,K]*W2[h,K] ---------------
// Block = one (split s, cs-half csx, msgrp); 4 waves = 4 M32 tiles
// (ms = w*16 + msgrp, ms%8 == bid%8 -> XCD-local G2 reads).
// Self-prep: W2 slice (64 h x 8 kc) f32 -> frag-linear LDS (32 KB), then
// 8 K-steps: A reg-dbuf from G2, B from LDS. s==0 folds +32*b2[h].
#define STEPG(CUR, NXT, KNR) do {                                              \
  _Pragma("unroll")                                                            \
  for (int mi = 0; mi < 2; ++mi)                                               \
    A[NXT][mi] = *(const bf16x8*)(Ab + (long)(kc0 + (KNR) + 1)*1024 + mi*128); \
  _Pragma("unroll")                                                            \
  for (int ni = 0; ni < 4; ++ni) {                                             \
    bf16x8 bfr = *(const bf16x8*)&ldsW[(KNR)*2048 + ni*512 + fo];              \
    _Pragma("unroll")                                                          \
    for (int mi = 0; mi < 2; ++mi)                                             \
      acc[mi][ni] = __builtin_amdgcn_mfma_f32_16x16x32_bf16(A[CUR][mi],        \
                                  bfr, acc[mi][ni], 0, 0, 0);                  \
  }                                                                            \
} while (0)

__global__ __launch_bounds__(256, 2) void gemm2(
    const bf16* __restrict__ G2, const float* __restrict__ W2,
    const float* __restrict__ b2, float* __restrict__ out)
{
  __shared__ __align__(16) bf16 ldsW[8*2048];     // 32,768 B
  const int t = threadIdx.x, bid = blockIdx.x;
  const int lane = t & 63, w = t >> 6;
  const int lr = lane & 15, lq = lane >> 4;
  const int fo = lq*128 + lr*8;
  const int x = bid & 7, u = bid >> 3;
  const int s = u >> 2, csx = (u >> 1) & 1, mhi = u & 1;
  const int msgrp = mhi*8 + x;
  const int ms = w*16 + msgrp;                    // ms%8 == bid%8
  const int kc0 = s*8;

  // ---- self-prep W2 slice -> LDS (tasks = (kcrel, hl), 2 rounds) ----
  #pragma unroll
  for (int r = 0; r < 2; ++r) {
    int task = r*256 + t;
    int kcrel = task >> 6, hl = task & 63;
    int h = csx*64 + hl, kc = kc0 + kcrel;
    const float* src = W2 + ((long)h*128 + kc)*NM;
    int dstb = kcrel*2048 + (hl >> 4)*512 + (hl & 15)*8;
    #pragma unroll
    for (int cq = 0; cq < 4; ++cq) {
      bf16x8 pk;
      #pragma unroll
      for (int el = 0; el < 8; ++el) {
        int c = cq*8 + el;
        pk[el] = (c < NM) ? (bf16)src[c] : (bf16)0.f;
      }
      *(bf16x8*)&ldsW[dstb + cq*128] = pk;
    }
  }
  __syncthreads();

  const bf16* Ab = G2 + ((long)(ms*512 + lq)*32 + lr)*8;

  f32x4 acc[2][4];
  #pragma unroll
  for (int mi=0; mi<2; ++mi)
    #pragma unroll
    for (int ni=0; ni<4; ++ni) acc[mi][ni] = {0.f,0.f,0.f,0.f};

  bf16x8 A[2][2];
  #pragma unroll
  for (int mi=0; mi<2; ++mi)
    A[0][mi] = *(const bf16x8*)(Ab + (long)kc0*1024 + mi*128);

  for (int jj = 0; jj < 4; ++jj) {
    STEPG(0, 1, 2*jj);
    STEPG(1, 0, 2*jj + 1);
  }

  if (s == 0) {                                   // fold +32*b2[h] (out zeroed)
    #pragma unroll
    for (int ni=0; ni<4; ++ni) {
      float bv = 32.0f * b2[csx*64 + ni*16 + lr];
      #pragma unroll
      for (int mi=0; mi<2; ++mi)
        #pragma unroll
        for (int r=0; r<4; ++r) acc[mi][ni][r] += bv;
    }
  }

  #pragma unroll
  for (int mi=0; mi<2; ++mi)
    #pragma unroll
    for (int ni=0; ni<4; ++ni) {
      int h = csx*64 + ni*16 + lr;
      #pragma unroll
      for (int r=0; r<4; ++r) {
        int b = ms*32 + mi*16 + lq*4 + r;
        atomicAdd(&out[b*256 + 128 + h], acc[mi][ni][r]);
      }
    }
}

// ---------------- launch ----------------
extern "C" void kernel_launch(void* const* d_in, const int* in_sizes, int n_in,
                              void* d_out, int out_size, void* d_ws, size_t ws_size,
                              hipStream_t stream) {
  const float* in = (const float*)d_in[0];
  const float* W1 = (const float*)d_in[1];
  const float* b1 = (const float*)d_in[2];
  const float* W2 = (const float*)d_in[3];
  const float* b2 = (const float*)d_in[4];
  float* out = (float*)d_out;

  bf16* G2 = (bf16*)((char*)d_ws + 4194304);  // 2048*4096*2 = 16,777,216

  cin1G<<<2048, 256, 0, stream>>>(in, W1, b1, G2, out);
  gemm2<<<512,  256, 0, stream>>>(G2, W2, b2, out);
}

// Round 6
// 111.438 us; speedup vs baseline: 1.1840x; 1.1840x over previous
//
#include <hip/hip_runtime.h>

typedef __bf16 bf16;
typedef __bf16 bf16x8 __attribute__((ext_vector_type(8)));
typedef __bf16 bf16x4 __attribute__((ext_vector_type(4)));
typedef float f32x4 __attribute__((ext_vector_type(4)));
typedef unsigned int u32;

#define NB    2048
#define NM    26
#define NJP   27      // 26 K-chunks + 1 zero pad (unconditional prefetch)

// ---------------- prep: frag-linear weight tiles ----------------------------
// Weight tiles FRAGMENT-LINEAR: in a 64x32 tile, element (r=ni*16+lr,
// c=lq*8+el) lives at ni*512 + lq*128 + lr*8 + el.
// 643,072 elems = 628 blocks * 256 thr * 4 strides exactly.
__global__ __launch_bounds__(256) void prep_all(
    const float* __restrict__ W1, const float* __restrict__ W2,
    bf16* __restrict__ w1t, bf16* __restrict__ w2t2)
{
  const int bid = blockIdx.x, t = threadIdx.x;
  #pragma unroll
  for (int g = 0; g < 4; ++g) {
    int ge = g*160768 + bid*256 + t;
    if (ge < 110592) {                    // w1t tiles [cs(2)][c(NJP)], frag-linear
      int e = ge;
      int el = e & 7, lr = (e >> 3) & 15, lq = (e >> 7) & 3, ni = (e >> 9) & 3;
      int rest = e >> 11;
      int c = rest % NJP, cs_idx = rest / NJP;
      int h = cs_idx*64 + ni*16 + lr;
      int i = lq*8 + el;
      float v = (i < NM && c < NM) ? W1[h*(NM*NM) + i*NM + c] : 0.f;
      w1t[e] = (bf16)v;
    } else {                              // w2t2 tiles [cs(2)][kc(130)], frag-linear
      int e = ge - 110592;                // flatK = kc*32 + c  (kc=i, c=j)
      int el = e & 7, lr = (e >> 3) & 15, lq = (e >> 7) & 3, ni = (e >> 9) & 3;
      int rest = e >> 11;                 // [0, 260)
      int kc = rest % 130, cs_idx = rest / 130;
      int h = cs_idx*64 + ni*16 + lr;
      int c = lq*8 + el;
      float v = (kc < 128 && c < NM) ? W2[h*(128*NM) + kc*NM + c] : 0.f;
      w2t2[e] = (bf16)v;
    }
  }
}

// cin1G K-chunk step: scalars (f32) + B-frags prefetched 1 ahead; compute
// chunk J for BOTH batches from buffer CUR. af built in f32 then converted
// (avoids scalarized bf16 VALU arithmetic).
#define STEP(CUR, NXT, J) do {                                                 \
  { int jn = ((J)+1 > 25) ? 25 : (J)+1;  /* chunk-26 weights are zero */       \
    scf[NXT][0][0] = spw0[jn*32];  scf[NXT][0][1] = spw0[jn*32 + 16];          \
    scf[NXT][1][0] = spw1[jn*32];  scf[NXT][1][1] = spw1[jn*32 + 16]; }        \
  _Pragma("unroll")                                                            \
  for (int ni = 0; ni < 4; ++ni)                                               \
    B[NXT][ni] = *(const bf16x8*)(tb + (long)((J)+1)*2048 + ni*512);           \
  _Pragma("unroll")                                                            \
  for (int bb = 0; bb < 2; ++bb)                                               \
    _Pragma("unroll")                                                          \
    for (int mi = 0; mi < 2; ++mi) {                                           \
      bf16x8 af;                                                               \
      _Pragma("unroll")                                                        \
      for (int e = 0; e < 8; ++e)                                              \
        af[e] = (bf16)(xf32[bb][mi][e] * scf[CUR][bb][mi]);                    \
      _Pragma("unroll")                                                        \
      for (int ni = 0; ni < 4; ++ni)                                           \
        acc[bb][mi][ni] = __builtin_amdgcn_mfma_f32_16x16x32_bf16(af,          \
                                    B[CUR][ni], acc[bb][mi][ni], 0, 0, 0);     \
    }                                                                          \
} while (0)

// ---------------- layer 1 + fused G: wave = 2 batches x one cs-half ----------
// B-frags read once per wave, shared by both batches (halves w1t L2 traffic,
// doubles MFMA ILP). Epilogue per batch: out-row, x1^T via wave-private LDS,
// swapped G-MFMA, vectorized tiled G2 stores.
__global__ __launch_bounds__(256, 2) void cin1G(
    const float* __restrict__ in, const bf16* __restrict__ w1t,
    const float* __restrict__ b1, bf16* __restrict__ G2, float* __restrict__ out)
{
  __shared__ __align__(16) bf16 ldsT[4][64*36];   // wave-private x1^T [i64][k32+pad]
  const int t = threadIdx.x, bid = blockIdx.x;
  const int lane = t & 63, w = t >> 6;
  const int lr = lane & 15, lq = lane >> 4;
  const int fo = lq*128 + lr*8;
  const int cs_idx = bid & 1, cs = cs_idx * 64;
  const int strip8 = bid >> 1;                    // 0..255, 8 batches each
  const int bw0 = strip8*8 + w*2;                 // this wave's batches bw0, bw0+1

  const float* bin0 = in + (long)bw0*(NM*32);
  const float* bin1 = bin0 + NM*32;
  const float* spw0 = bin0 + lr;                  // + j*32 + mi*16 (k = mi*16+lr)
  const float* spw1 = bin1 + lr;

  // x0 A-frags in f32: xf32[bb][mi][e] = x0[bw0+bb][j=lq*8+e][k=mi*16+lr]
  float xf32[2][2][8];
  #pragma unroll
  for (int bb = 0; bb < 2; ++bb) {
    const float* bin = bb ? bin1 : bin0;
    #pragma unroll
    for (int mi = 0; mi < 2; ++mi)
      #pragma unroll
      for (int e = 0; e < 8; ++e) {
        int j = lq*8 + e;
        xf32[bb][mi][e] = (j < NM) ? bin[j*32 + mi*16 + lr] : 0.f;
      }
  }

  f32x4 acc[2][2][4];
  #pragma unroll
  for (int bb=0; bb<2; ++bb)
    #pragma unroll
    for (int mi=0; mi<2; ++mi)
      #pragma unroll
      for (int ni=0; ni<4; ++ni) acc[bb][mi][ni] = {0.f,0.f,0.f,0.f};

  const bf16* tb = w1t + (long)cs_idx*NJP*2048 + fo;

  float scf[2][2][2];
  bf16x8 B[2][4];
  #pragma unroll
  for (int ni = 0; ni < 4; ++ni)
    B[0][ni] = *(const bf16x8*)(tb + ni*512);     // chunk 0
  scf[0][0][0] = spw0[0];  scf[0][0][1] = spw0[16];
  scf[0][1][0] = spw1[0];  scf[0][1][1] = spw1[16];

  for (int jj = 0; jj < 13; ++jj) {
    STEP(0, 1, 2*jj);
    STEP(1, 0, 2*jj + 1);
  }

  float bias[4];
  #pragma unroll
  for (int ni=0; ni<4; ++ni) bias[ni] = b1[cs + ni*16 + lr];

  bf16* T = &ldsT[w][0];

  #pragma unroll
  for (int bb = 0; bb < 2; ++bb) {
    const int bw = bw0 + bb;
    const float* bin = bb ? bin1 : bin0;

    // out[bw][cs:cs+64] = k-sum of x1 + 32*bias
    #pragma unroll
    for (int ni=0; ni<4; ++ni) {
      float vv = 0.f;
      #pragma unroll
      for (int mi=0; mi<2; ++mi)
        #pragma unroll
        for (int r=0; r<4; ++r) vv += acc[bb][mi][ni][r];
      vv += __shfl_xor(vv, 16, 64);
      vv += __shfl_xor(vv, 32, 64);
      if (lq == 0) out[bw*256 + cs + ni*16 + lr] = vv + 32.0f * bias[ni];
    }

    // x1 (C-layout) -> wave-private LDS [i_local][k], row stride 36
    #pragma unroll
    for (int mi=0; mi<2; ++mi)
      #pragma unroll
      for (int ni=0; ni<4; ++ni) {
        bf16x4 pk;
        #pragma unroll
        for (int r=0; r<4; ++r) pk[r] = (bf16)(acc[bb][mi][ni][r] + bias[ni]);
        *(bf16x4*)&T[(ni*16+lr)*36 + mi*16 + lq*4] = pk;
      }
    // no barrier: wave-private tile; same-wave DS ordering protects reuse

    // B-frags: x0[j][k] from in
    bf16x8 bg[2];
    #pragma unroll
    for (int nt = 0; nt < 2; ++nt) {
      int j = nt*16 + lr;
      bf16x8 vv;
      #pragma unroll
      for (int e=0; e<8; ++e) vv[e] = (bf16)0.f;
      if (j < NM) {
        const float* src = bin + j*32 + lq*8;
        f32x4 a = *(const f32x4*)src, c = *(const f32x4*)(src+4);
        #pragma unroll
        for (int e=0; e<4; ++e) { vv[e] = (bf16)a[e]; vv[4+e] = (bf16)c[e]; }
      }
      bg[nt] = vv;
    }
    // swapped G-MFMAs + vectorized tiled G2 stores
    const long gbase = (long)(bw >> 5)*131072 + (bw & 31)*8;
    #pragma unroll
    for (int mt = 0; mt < 4; ++mt) {
      bf16x8 ag = *(const bf16x8*)&T[(mt*16+lr)*36 + lq*8];
      #pragma unroll
      for (int nt = 0; nt < 2; ++nt) {
        f32x4 z = {0.f,0.f,0.f,0.f};
        f32x4 g = __builtin_amdgcn_mfma_f32_16x16x32_bf16(bg[nt], ag, z, 0, 0, 0);
        // lane holds G[bw][i=cs+mt*16+lr][j=nt*16+lq*4+r]
        bf16x4 pk;
        #pragma unroll
        for (int r = 0; r < 4; ++r) pk[r] = (bf16)g[r];
        const int kh = (cs + mt*16 + lr)*4 + nt*2 + (lq >> 1);
        *(bf16x4*)&G2[gbase + (long)kh*256 + (lq & 1)*4] = pk;
      }
    }
  }
}

// ---------------- gemm2: out[b][128+h] += sum_K G[b][K]*W2p[h][K] -------------
// M=2048 b (tiles of 32), N=128 h, K=4096 flat; split-K x16; atomics into out
// (L2-resident). s==0 folds the +32*b2[h] bias (out is zeroed by harness).
#define STEPG(CUR, NXT, KN) do {                                               \
  _Pragma("unroll")                                                            \
  for (int mi = 0; mi < 2; ++mi)                                               \
    A[NXT][mi] = *(const bf16x8*)(Ab + (long)(KN)*1024 + mi*128);              \
  _Pragma("unroll")                                                            \
  for (int ni = 0; ni < 4; ++ni)                                               \
    B[NXT][ni] = *(const bf16x8*)(tbc + (long)(KN)*2048 + ni*512);             \
  _Pragma("unroll")                                                            \
  for (int mi = 0; mi < 2; ++mi)                                               \
    _Pragma("unroll")                                                          \
    for (int ni = 0; ni < 4; ++ni)                                             \
      acc[mi][ni] = __builtin_amdgcn_mfma_f32_16x16x32_bf16(A[CUR][mi],        \
                                  B[CUR][ni], acc[mi][ni], 0, 0, 0);           \
} while (0)

__global__ __launch_bounds__(256, 4) void gemm2(
    const bf16* __restrict__ G2, const bf16* __restrict__ w2t2,
    const float* __restrict__ b2, float* __restrict__ out)
{
  const int t = threadIdx.x;
  const int lane = t & 63, w = t >> 6;
  const int s = blockIdx.x >> 5;              // 16 splits
  const int q32 = blockIdx.x & 31;
  const int x = q32 & 7, q = q32 >> 3;
  const int ms = x + q*16 + (w >> 1)*8;
  const int cs_idx = w & 1;
  const int lr = lane & 15, lq = lane >> 4;
  const int fo = lq*128 + lr*8;
  const int kc0 = s*8;

  const bf16* Ab  = G2 + ((long)(ms*512 + lq)*32 + lr)*8;
  const bf16* tbc = w2t2 + (long)cs_idx*130*2048 + fo;

  f32x4 acc[2][4];
  #pragma unroll
  for (int mi=0; mi<2; ++mi)
    #pragma unroll
    for (int ni=0; ni<4; ++ni) acc[mi][ni] = {0.f,0.f,0.f,0.f};

  bf16x8 A[2][2], B[2][4];
  #pragma unroll
  for (int mi=0; mi<2; ++mi)
    A[0][mi] = *(const bf16x8*)(Ab + (long)kc0*1024 + mi*128);
  #pragma unroll
  for (int ni=0; ni<4; ++ni)
    B[0][ni] = *(const bf16x8*)(tbc + (long)kc0*2048 + ni*512);

  for (int jj = 0; jj < 4; ++jj) {
    STEPG(0, 1, kc0 + 2*jj + 1);
    STEPG(1, 0, kc0 + 2*jj + 2);
  }

  if (s == 0) {                               // fold +32*b2[h] (out starts at 0)
    #pragma unroll
    for (int ni=0; ni<4; ++ni) {
      float bv = 32.0f * b2[cs_idx*64 + ni*16 + lr];
      #pragma unroll
      for (int mi=0; mi<2; ++mi)
        #pragma unroll
        for (int r=0; r<4; ++r) acc[mi][ni][r] += bv;
    }
  }

  #pragma unroll
  for (int mi=0; mi<2; ++mi)
    #pragma unroll
    for (int ni=0; ni<4; ++ni) {
      int h = cs_idx*64 + ni*16 + lr;
      #pragma unroll
      for (int r=0; r<4; ++r) {
        int b = ms*32 + mi*16 + lq*4 + r;
        atomicAdd(&out[b*256 + 128 + h], acc[mi][ni][r]);
      }
    }
}

// ---------------- launch ----------------
extern "C" void kernel_launch(void* const* d_in, const int* in_sizes, int n_in,
                              void* d_out, int out_size, void* d_ws, size_t ws_size,
                              hipStream_t stream) {
  const float* in = (const float*)d_in[0];
  const float* W1 = (const float*)d_in[1];
  const float* b1 = (const float*)d_in[2];
  const float* W2 = (const float*)d_in[3];
  const float* b2 = (const float*)d_in[4];
  float* out = (float*)d_out;

  char* ws = (char*)d_ws;
  bf16* w1t  = (bf16*)(ws);                 // 2*27*2048*2  = 221,184
  bf16* w2t2 = (bf16*)(ws + 1048576);       // 2*130*2048*2 = 1,064,960
  bf16* G2   = (bf16*)(ws + 4194304);       // 2048*4096*2  = 16,777,216 (end ~21 MB)

  prep_all<<<628, 256, 0, stream>>>(W1, W2, w1t, w2t2);
  cin1G  <<<512, 256, 0, stream>>>(in, w1t, b1, G2, out);
  gemm2  <<<512, 256, 0, stream>>>(G2, w2t2, b2, out);
}

// Round 7
// 105.659 us; speedup vs baseline: 1.2488x; 1.0547x over previous
//
#include <hip/hip_runtime.h>

typedef __bf16 bf16;
typedef __bf16 bf16x8 __attribute__((ext_vector_type(8)));
typedef __bf16 bf16x4 __attribute__((ext_vector_type(4)));
typedef float f32x4 __attribute__((ext_vector_type(4)));
typedef unsigned int u32;

#define NB    2048
#define NM    26
#define NJP   27      // 26 K-chunks + 1 zero pad (unconditional prefetch)

// ---------------- prep: frag-linear W1 tiles only ----------------------------
// In a 64x32 tile, element (r=ni*16+lr, c=lq*8+el) lives at
// ni*512 + lq*128 + lr*8 + el.  110,592 elems = 432 blocks * 256 exactly.
__global__ __launch_bounds__(256) void prep_all(
    const float* __restrict__ W1, bf16* __restrict__ w1t)
{
  int e = blockIdx.x*256 + threadIdx.x;
  int el = e & 7, lr = (e >> 3) & 15, lq = (e >> 7) & 3, ni = (e >> 9) & 3;
  int rest = e >> 11;
  int c = rest % NJP, cs_idx = rest / NJP;
  int h = cs_idx*64 + ni*16 + lr;
  int i = lq*8 + el;
  float v = (i < NM && c < NM) ? W1[h*(NM*NM) + i*NM + c] : 0.f;
  w1t[e] = (bf16)v;
}

// cin1G K-chunk step: scalars (f32) + B-frags prefetched 1 ahead; compute
// chunk J for BOTH batches from buffer CUR. af built in f32 then converted
// (avoids scalarized bf16 VALU arithmetic).
#define STEP(CUR, NXT, J) do {                                                 \
  { int jn = ((J)+1 > 25) ? 25 : (J)+1;  /* chunk-26 weights are zero */       \
    scf[NXT][0][0] = spw0[jn*32];  scf[NXT][0][1] = spw0[jn*32 + 16];          \
    scf[NXT][1][0] = spw1[jn*32];  scf[NXT][1][1] = spw1[jn*32 + 16]; }        \
  _Pragma("unroll")                                                            \
  for (int ni = 0; ni < 4; ++ni)                                               \
    B[NXT][ni] = *(const bf16x8*)(tb + (long)((J)+1)*2048 + ni*512);           \
  _Pragma("unroll")                                                            \
  for (int bb = 0; bb < 2; ++bb)                                               \
    _Pragma("unroll")                                                          \
    for (int mi = 0; mi < 2; ++mi) {                                           \
      bf16x8 af;                                                               \
      _Pragma("unroll")                                                        \
      for (int e = 0; e < 8; ++e)                                              \
        af[e] = (bf16)(xf32[bb][mi][e] * scf[CUR][bb][mi]);                    \
      _Pragma("unroll")                                                        \
      for (int ni = 0; ni < 4; ++ni)                                           \
        acc[bb][mi][ni] = __builtin_amdgcn_mfma_f32_16x16x32_bf16(af,          \
                                    B[CUR][ni], acc[bb][mi][ni], 0, 0, 0);     \
    }                                                                          \
} while (0)

// ---------------- layer 1 + fused G: wave = 2 batches x one cs-half ----------
// B-frags read once per wave, shared by both batches (halves w1t L2 traffic,
// doubles MFMA ILP). Epilogue per batch: out-row, x1^T via wave-private LDS,
// swapped G-MFMA, vectorized tiled G2 stores.
__global__ __launch_bounds__(256, 2) void cin1G(
    const float* __restrict__ in, const bf16* __restrict__ w1t,
    const float* __restrict__ b1, bf16* __restrict__ G2, float* __restrict__ out)
{
  __shared__ __align__(16) bf16 ldsT[4][64*36];   // wave-private x1^T [i64][k32+pad]
  const int t = threadIdx.x, bid = blockIdx.x;
  const int lane = t & 63, w = t >> 6;
  const int lr = lane & 15, lq = lane >> 4;
  const int fo = lq*128 + lr*8;
  const int cs_idx = bid & 1, cs = cs_idx * 64;
  const int strip8 = bid >> 1;                    // 0..255, 8 batches each
  const int bw0 = strip8*8 + w*2;                 // this wave's batches bw0, bw0+1

  const float* bin0 = in + (long)bw0*(NM*32);
  const float* bin1 = bin0 + NM*32;
  const float* spw0 = bin0 + lr;                  // + j*32 + mi*16 (k = mi*16+lr)
  const float* spw1 = bin1 + lr;

  // x0 A-frags in f32: xf32[bb][mi][e] = x0[bw0+bb][j=lq*8+e][k=mi*16+lr]
  float xf32[2][2][8];
  #pragma unroll
  for (int bb = 0; bb < 2; ++bb) {
    const float* bin = bb ? bin1 : bin0;
    #pragma unroll
    for (int mi = 0; mi < 2; ++mi)
      #pragma unroll
      for (int e = 0; e < 8; ++e) {
        int j = lq*8 + e;
        xf32[bb][mi][e] = (j < NM) ? bin[j*32 + mi*16 + lr] : 0.f;
      }
  }

  f32x4 acc[2][2][4];
  #pragma unroll
  for (int bb=0; bb<2; ++bb)
    #pragma unroll
    for (int mi=0; mi<2; ++mi)
      #pragma unroll
      for (int ni=0; ni<4; ++ni) acc[bb][mi][ni] = {0.f,0.f,0.f,0.f};

  const bf16* tb = w1t + (long)cs_idx*NJP*2048 + fo;

  float scf[2][2][2];
  bf16x8 B[2][4];
  #pragma unroll
  for (int ni = 0; ni < 4; ++ni)
    B[0][ni] = *(const bf16x8*)(tb + ni*512);     // chunk 0
  scf[0][0][0] = spw0[0];  scf[0][0][1] = spw0[16];
  scf[0][1][0] = spw1[0];  scf[0][1][1] = spw1[16];

  for (int jj = 0; jj < 13; ++jj) {
    STEP(0, 1, 2*jj);
    STEP(1, 0, 2*jj + 1);
  }

  float bias[4];
  #pragma unroll
  for (int ni=0; ni<4; ++ni) bias[ni] = b1[cs + ni*16 + lr];

  bf16* T = &ldsT[w][0];

  #pragma unroll
  for (int bb = 0; bb < 2; ++bb) {
    const int bw = bw0 + bb;
    const float* bin = bb ? bin1 : bin0;

    // out[bw][cs:cs+64] = k-sum of x1 + 32*bias
    #pragma unroll
    for (int ni=0; ni<4; ++ni) {
      float vv = 0.f;
      #pragma unroll
      for (int mi=0; mi<2; ++mi)
        #pragma unroll
        for (int r=0; r<4; ++r) vv += acc[bb][mi][ni][r];
      vv += __shfl_xor(vv, 16, 64);
      vv += __shfl_xor(vv, 32, 64);
      if (lq == 0) out[bw*256 + cs + ni*16 + lr] = vv + 32.0f * bias[ni];
    }

    // x1 (C-layout) -> wave-private LDS [i_local][k], row stride 36
    #pragma unroll
    for (int mi=0; mi<2; ++mi)
      #pragma unroll
      for (int ni=0; ni<4; ++ni) {
        bf16x4 pk;
        #pragma unroll
        for (int r=0; r<4; ++r) pk[r] = (bf16)(acc[bb][mi][ni][r] + bias[ni]);
        *(bf16x4*)&T[(ni*16+lr)*36 + mi*16 + lq*4] = pk;
      }
    // no barrier: wave-private tile; same-wave DS ordering protects reuse

    // B-frags: x0[j][k] from in
    bf16x8 bg[2];
    #pragma unroll
    for (int nt = 0; nt < 2; ++nt) {
      int j = nt*16 + lr;
      bf16x8 vv;
      #pragma unroll
      for (int e=0; e<8; ++e) vv[e] = (bf16)0.f;
      if (j < NM) {
        const float* src = bin + j*32 + lq*8;
        f32x4 a = *(const f32x4*)src, c = *(const f32x4*)(src+4);
        #pragma unroll
        for (int e=0; e<4; ++e) { vv[e] = (bf16)a[e]; vv[4+e] = (bf16)c[e]; }
      }
      bg[nt] = vv;
    }
    // swapped G-MFMAs + vectorized tiled G2 stores
    const long gbase = (long)(bw >> 5)*131072 + (bw & 31)*8;
    #pragma unroll
    for (int mt = 0; mt < 4; ++mt) {
      bf16x8 ag = *(const bf16x8*)&T[(mt*16+lr)*36 + lq*8];
      #pragma unroll
      for (int nt = 0; nt < 2; ++nt) {
        f32x4 z = {0.f,0.f,0.f,0.f};
        f32x4 g = __builtin_amdgcn_mfma_f32_16x16x32_bf16(bg[nt], ag, z, 0, 0, 0);
        // lane holds G[bw][i=cs+mt*16+lr][j=nt*16+lq*4+r]
        bf16x4 pk;
        #pragma unroll
        for (int r = 0; r < 4; ++r) pk[r] = (bf16)g[r];
        const int kh = (cs + mt*16 + lr)*4 + nt*2 + (lq >> 1);
        *(bf16x4*)&G2[gbase + (long)kh*256 + (lq & 1)*4] = pk;
      }
    }
  }
}

// ---------------- gemm2: out[b][128+h] += sum_K G[b,K]*W2[h,K] ---------------
// M=2048 b (M16 tiles), N=128 h (64 per block), K=4096 flat; split-K x8.
// Block = (split s, cs-half, group of 4 M16 tiles); self-preps its W2 slice
// (64 h x 16 kc) f32 -> frag-linear 64KB LDS shared by all 4 waves.
// A reg-dbuf from G2 (L2); B from LDS. s==0 folds +32*b2[h] (out zeroed).
#define STEPG(CUR, NXT, KREL) do {                                             \
  A[NXT] = *(const bf16x8*)(Ab + (long)(kc0 + (KREL) + 1)*1024);               \
  _Pragma("unroll")                                                            \
  for (int ni = 0; ni < 4; ++ni) {                                             \
    bf16x8 bfr = *(const bf16x8*)&ldsW[(KREL)*2048 + ni*512 + fo];             \
    acc[ni] = __builtin_amdgcn_mfma_f32_16x16x32_bf16(A[CUR], bfr,             \
                                                      acc[ni], 0, 0, 0);       \
  }                                                                            \
} while (0)

__global__ __launch_bounds__(256, 2) void gemm2(
    const bf16* __restrict__ G2, const float* __restrict__ W2,
    const float* __restrict__ b2, float* __restrict__ out)
{
  __shared__ __align__(16) bf16 ldsW[16*2048];    // 65,536 B
  const int t = threadIdx.x, bid = blockIdx.x;
  const int lane = t & 63, w = t >> 6;
  const int lr = lane & 15, lq = lane >> 4;
  const int fo = lq*128 + lr*8;
  const int s = bid & 7;                          // splits spread across XCDs
  const int csx = (bid >> 3) & 1;
  const int g = bid >> 4;                         // 0..31
  const int ms16 = g*4 + w;                       // this wave's M16 tile
  const int ms32 = ms16 >> 1, mif = ms16 & 1;
  const int kc0 = s*16;

  // ---- self-prep W2 slice (64 h x 16 kc) -> frag-linear LDS, 4 rounds ----
  #pragma unroll
  for (int r = 0; r < 4; ++r) {
    int task = r*256 + t;
    int kcrel = task >> 6, hl = task & 63;
    int h = csx*64 + hl, kc = kc0 + kcrel;
    const float* src = W2 + ((long)h*128 + kc)*NM;
    int dstb = kcrel*2048 + (hl >> 4)*512 + (hl & 15)*8;
    #pragma unroll
    for (int cq = 0; cq < 4; ++cq) {
      bf16x8 pk;
      #pragma unroll
      for (int el = 0; el < 8; ++el) {
        int c = cq*8 + el;
        pk[el] = (c < NM) ? (bf16)src[c] : (bf16)0.f;
      }
      *(bf16x8*)&ldsW[dstb + cq*128] = pk;
    }
  }
  __syncthreads();

  // A-frag base: lane(lr,lq) reads batch ms16*16+lr, flatK = kc*32 + lq*8..+8
  const bf16* Ab = G2 + (long)ms32*131072 + mif*128 + lq*256 + lr*8;

  f32x4 acc[4];
  #pragma unroll
  for (int ni=0; ni<4; ++ni) acc[ni] = {0.f,0.f,0.f,0.f};

  bf16x8 A[2];
  A[0] = *(const bf16x8*)(Ab + (long)kc0*1024);

  for (int jj = 0; jj < 8; ++jj) {
    STEPG(0, 1, 2*jj);
    STEPG(1, 0, 2*jj + 1);
  }

  if (s == 0) {                                   // fold +32*b2[h] (out zeroed)
    #pragma unroll
    for (int ni=0; ni<4; ++ni) {
      float bv = 32.0f * b2[csx*64 + ni*16 + lr];
      #pragma unroll
      for (int r=0; r<4; ++r) acc[ni][r] += bv;
    }
  }

  #pragma unroll
  for (int ni=0; ni<4; ++ni) {
    int h = csx*64 + ni*16 + lr;
    #pragma unroll
    for (int r=0; r<4; ++r) {
      int b = ms16*16 + lq*4 + r;
      atomicAdd(&out[b*256 + 128 + h], acc[ni][r]);
    }
  }
}

// ---------------- launch ----------------
extern "C" void kernel_launch(void* const* d_in, const int* in_sizes, int n_in,
                              void* d_out, int out_size, void* d_ws, size_t ws_size,
                              hipStream_t stream) {
  const float* in = (const float*)d_in[0];
  const float* W1 = (const float*)d_in[1];
  const float* b1 = (const float*)d_in[2];
  const float* W2 = (const float*)d_in[3];
  const float* b2 = (const float*)d_in[4];
  float* out = (float*)d_out;

  char* ws = (char*)d_ws;
  bf16* w1t = (bf16*)(ws);                  // 2*27*2048*2 = 221,184
  bf16* G2  = (bf16*)(ws + 4194304);        // 2048*4096*2 = 16,777,216 (end ~21 MB)

  prep_all<<<432, 256, 0, stream>>>(W1, w1t);
  cin1G  <<<512, 256, 0, stream>>>(in, w1t, b1, G2, out);
  gemm2  <<<512, 256, 0, stream>>>(G2, W2, b2, out);
}

// Round 8
// 102.018 us; speedup vs baseline: 1.2933x; 1.0357x over previous
//
#include <hip/hip_runtime.h>

typedef __bf16 bf16;
typedef __bf16 bf16x8 __attribute__((ext_vector_type(8)));
typedef __bf16 bf16x4 __attribute__((ext_vector_type(4)));
typedef float f32x4 __attribute__((ext_vector_type(4)));
typedef unsigned int u32;

#define NB    2048
#define NM    26
#define NJP   27      // 26 K-chunks + 1 zero pad (unconditional prefetch)

__device__ __forceinline__ void gl_lds16(const bf16* g, bf16* l) {
  __builtin_amdgcn_global_load_lds(
      (const __attribute__((address_space(1))) void*)g,
      (__attribute__((address_space(3))) void*)l, 16, 0, 0);
}

// ---------------- prep: frag-linear weight tiles (w1t + w2t2) ----------------
// In a 64x32 tile, element (r=ni*16+lr, c=lq*8+el) lives at
// ni*512 + lq*128 + lr*8 + el.  643,072 elems = 628 blocks * 256 * 4 exactly.
__global__ __launch_bounds__(256) void prep_all(
    const float* __restrict__ W1, const float* __restrict__ W2,
    bf16* __restrict__ w1t, bf16* __restrict__ w2t2)
{
  const int bid = blockIdx.x, t = threadIdx.x;
  #pragma unroll
  for (int g = 0; g < 4; ++g) {
    int ge = g*160768 + bid*256 + t;
    if (ge < 110592) {                    // w1t tiles [cs(2)][c(NJP)], frag-linear
      int e = ge;
      int el = e & 7, lr = (e >> 3) & 15, lq = (e >> 7) & 3, ni = (e >> 9) & 3;
      int rest = e >> 11;
      int c = rest % NJP, cs_idx = rest / NJP;
      int h = cs_idx*64 + ni*16 + lr;
      int i = lq*8 + el;
      float v = (i < NM && c < NM) ? W1[h*(NM*NM) + i*NM + c] : 0.f;
      w1t[e] = (bf16)v;
    } else {                              // w2t2 tiles [cs(2)][kc(130)], frag-linear
      int e = ge - 110592;                // flatK = kc*32 + c  (kc=i, c=j)
      int el = e & 7, lr = (e >> 3) & 15, lq = (e >> 7) & 3, ni = (e >> 9) & 3;
      int rest = e >> 11;                 // [0, 260)
      int kc = rest % 130, cs_idx = rest / 130;
      int h = cs_idx*64 + ni*16 + lr;
      int c = lq*8 + el;
      float v = (kc < 128 && c < NM) ? W2[h*(128*NM) + kc*NM + c] : 0.f;
      w2t2[e] = (bf16)v;
    }
  }
}

// cin1G K-chunk step: scalars (f32) + B-frags prefetched 1 ahead; compute
// chunk J for BOTH batches from buffer CUR. af built in f32 then converted
// (avoids scalarized bf16 VALU arithmetic).
#define STEP(CUR, NXT, J) do {                                                 \
  { int jn = ((J)+1 > 25) ? 25 : (J)+1;  /* chunk-26 weights are zero */       \
    scf[NXT][0][0] = spw0[jn*32];  scf[NXT][0][1] = spw0[jn*32 + 16];          \
    scf[NXT][1][0] = spw1[jn*32];  scf[NXT][1][1] = spw1[jn*32 + 16]; }        \
  _Pragma("unroll")                                                            \
  for (int ni = 0; ni < 4; ++ni)                                               \
    B[NXT][ni] = *(const bf16x8*)(tb + (long)((J)+1)*2048 + ni*512);           \
  _Pragma("unroll")                                                            \
  for (int bb = 0; bb < 2; ++bb)                                               \
    _Pragma("unroll")                                                          \
    for (int mi = 0; mi < 2; ++mi) {                                           \
      bf16x8 af;                                                               \
      _Pragma("unroll")                                                        \
      for (int e = 0; e < 8; ++e)                                              \
        af[e] = (bf16)(xf32[bb][mi][e] * scf[CUR][bb][mi]);                    \
      _Pragma("unroll")                                                        \
      for (int ni = 0; ni < 4; ++ni)                                           \
        acc[bb][mi][ni] = __builtin_amdgcn_mfma_f32_16x16x32_bf16(af,          \
                                    B[CUR][ni], acc[bb][mi][ni], 0, 0, 0);     \
    }                                                                          \
} while (0)

// ---------------- layer 1 + fused G: wave = 2 batches x one cs-half ----------
// B-frags read once per wave, shared by both batches (halves w1t L2 traffic,
// doubles MFMA ILP). Epilogue per batch: out-row, x1^T via wave-private LDS,
// swapped G-MFMA, vectorized tiled G2 stores.
__global__ __launch_bounds__(256, 2) void cin1G(
    const float* __restrict__ in, const bf16* __restrict__ w1t,
    const float* __restrict__ b1, bf16* __restrict__ G2, float* __restrict__ out)
{
  __shared__ __align__(16) bf16 ldsT[4][64*36];   // wave-private x1^T [i64][k32+pad]
  const int t = threadIdx.x, bid = blockIdx.x;
  const int lane = t & 63, w = t >> 6;
  const int lr = lane & 15, lq = lane >> 4;
  const int fo = lq*128 + lr*8;
  const int cs_idx = bid & 1, cs = cs_idx * 64;
  const int strip8 = bid >> 1;                    // 0..255, 8 batches each
  const int bw0 = strip8*8 + w*2;                 // this wave's batches bw0, bw0+1

  const float* bin0 = in + (long)bw0*(NM*32);
  const float* bin1 = bin0 + NM*32;
  const float* spw0 = bin0 + lr;                  // + j*32 + mi*16 (k = mi*16+lr)
  const float* spw1 = bin1 + lr;

  // x0 A-frags in f32: xf32[bb][mi][e] = x0[bw0+bb][j=lq*8+e][k=mi*16+lr]
  float xf32[2][2][8];
  #pragma unroll
  for (int bb = 0; bb < 2; ++bb) {
    const float* bin = bb ? bin1 : bin0;
    #pragma unroll
    for (int mi = 0; mi < 2; ++mi)
      #pragma unroll
      for (int e = 0; e < 8; ++e) {
        int j = lq*8 + e;
        xf32[bb][mi][e] = (j < NM) ? bin[j*32 + mi*16 + lr] : 0.f;
      }
  }

  f32x4 acc[2][2][4];
  #pragma unroll
  for (int bb=0; bb<2; ++bb)
    #pragma unroll
    for (int mi=0; mi<2; ++mi)
      #pragma unroll
      for (int ni=0; ni<4; ++ni) acc[bb][mi][ni] = {0.f,0.f,0.f,0.f};

  const bf16* tb = w1t + (long)cs_idx*NJP*2048 + fo;

  float scf[2][2][2];
  bf16x8 B[2][4];
  #pragma unroll
  for (int ni = 0; ni < 4; ++ni)
    B[0][ni] = *(const bf16x8*)(tb + ni*512);     // chunk 0
  scf[0][0][0] = spw0[0];  scf[0][0][1] = spw0[16];
  scf[0][1][0] = spw1[0];  scf[0][1][1] = spw1[16];

  for (int jj = 0; jj < 13; ++jj) {
    STEP(0, 1, 2*jj);
    STEP(1, 0, 2*jj + 1);
  }

  float bias[4];
  #pragma unroll
  for (int ni=0; ni<4; ++ni) bias[ni] = b1[cs + ni*16 + lr];

  bf16* T = &ldsT[w][0];

  #pragma unroll
  for (int bb = 0; bb < 2; ++bb) {
    const int bw = bw0 + bb;
    const float* bin = bb ? bin1 : bin0;

    // out[bw][cs:cs+64] = k-sum of x1 + 32*bias
    #pragma unroll
    for (int ni=0; ni<4; ++ni) {
      float vv = 0.f;
      #pragma unroll
      for (int mi=0; mi<2; ++mi)
        #pragma unroll
        for (int r=0; r<4; ++r) vv += acc[bb][mi][ni][r];
      vv += __shfl_xor(vv, 16, 64);
      vv += __shfl_xor(vv, 32, 64);
      if (lq == 0) out[bw*256 + cs + ni*16 + lr] = vv + 32.0f * bias[ni];
    }

    // x1 (C-layout) -> wave-private LDS [i_local][k], row stride 36
    #pragma unroll
    for (int mi=0; mi<2; ++mi)
      #pragma unroll
      for (int ni=0; ni<4; ++ni) {
        bf16x4 pk;
        #pragma unroll
        for (int r=0; r<4; ++r) pk[r] = (bf16)(acc[bb][mi][ni][r] + bias[ni]);
        *(bf16x4*)&T[(ni*16+lr)*36 + mi*16 + lq*4] = pk;
      }
    // no barrier: wave-private tile; same-wave DS ordering protects reuse

    // B-frags: x0[j][k] from in
    bf16x8 bg[2];
    #pragma unroll
    for (int nt = 0; nt < 2; ++nt) {
      int j = nt*16 + lr;
      bf16x8 vv;
      #pragma unroll
      for (int e=0; e<8; ++e) vv[e] = (bf16)0.f;
      if (j < NM) {
        const float* src = bin + j*32 + lq*8;
        f32x4 a = *(const f32x4*)src, c = *(const f32x4*)(src+4);
        #pragma unroll
        for (int e=0; e<4; ++e) { vv[e] = (bf16)a[e]; vv[4+e] = (bf16)c[e]; }
      }
      bg[nt] = vv;
    }
    // swapped G-MFMAs + vectorized tiled G2 stores
    const long gbase = (long)(bw >> 5)*131072 + (bw & 31)*8;
    #pragma unroll
    for (int mt = 0; mt < 4; ++mt) {
      bf16x8 ag = *(const bf16x8*)&T[(mt*16+lr)*36 + lq*8];
      #pragma unroll
      for (int nt = 0; nt < 2; ++nt) {
        f32x4 z = {0.f,0.f,0.f,0.f};
        f32x4 g = __builtin_amdgcn_mfma_f32_16x16x32_bf16(bg[nt], ag, z, 0, 0, 0);
        // lane holds G[bw][i=cs+mt*16+lr][j=nt*16+lq*4+r]
        bf16x4 pk;
        #pragma unroll
        for (int r = 0; r < 4; ++r) pk[r] = (bf16)g[r];
        const int kh = (cs + mt*16 + lr)*4 + nt*2 + (lq >> 1);
        *(bf16x4*)&G2[gbase + (long)kh*256 + (lq & 1)*4] = pk;
      }
    }
  }
}

// ---------------- gemm2: out[b][128+h] += sum_K G[b,K]*W2p[h,K] --------------
// M=2048 b (M16 tiles), N=128 h (64 per block), K=4096 flat; split-K x8.
// Block = (split s, cs-half, group of 4 M16 tiles). B-tile (64h x 16kc) is a
// CONTIGUOUS 64 KB frag-linear slice of w2t2 -> staged via global_load_lds
// width-16 (zero VALU, zero VGPR round-trip). A reg-dbuf from G2 (L2).
// s==0 folds +32*b2[h] (out zeroed by harness).
#define STEPG(CUR, NXT, KREL) do {                                             \
  A[NXT] = *(const bf16x8*)(Ab + (long)(kc0 + (KREL) + 1)*1024);               \
  _Pragma("unroll")                                                            \
  for (int ni = 0; ni < 4; ++ni) {                                             \
    bf16x8 bfr = *(const bf16x8*)&ldsW[(KREL)*2048 + ni*512 + fo];             \
    acc[ni] = __builtin_amdgcn_mfma_f32_16x16x32_bf16(A[CUR], bfr,             \
                                                      acc[ni], 0, 0, 0);       \
  }                                                                            \
} while (0)

__global__ __launch_bounds__(256, 2) void gemm2(
    const bf16* __restrict__ G2, const bf16* __restrict__ w2t2,
    const float* __restrict__ b2, float* __restrict__ out)
{
  __shared__ __align__(16) bf16 ldsW[16*2048];    // 65,536 B
  const int t = threadIdx.x, bid = blockIdx.x;
  const int lane = t & 63, w = t >> 6;
  const int lr = lane & 15, lq = lane >> 4;
  const int fo = lq*128 + lr*8;
  const int s = bid & 7;                          // splits spread across XCDs
  const int csx = (bid >> 3) & 1;
  const int g = bid >> 4;                         // 0..31
  const int ms16 = g*4 + w;                       // this wave's M16 tile
  const int ms32 = ms16 >> 1, mif = ms16 & 1;
  const int kc0 = s*16;

  // ---- stage W2 slice (64h x 16kc = contiguous 64 KB of w2t2) -> LDS ----
  {
    const bf16* src = w2t2 + ((long)csx*130 + kc0)*2048;
    #pragma unroll
    for (int i = 0; i < 16; ++i)
      gl_lds16(src + i*2048 + t*8, &ldsW[i*2048 + t*8]);
  }
  __syncthreads();                                // drains vmcnt (gl_lds done)

  // A-frag base: lane(lr,lq) reads batch ms16*16+lr, flatK = kc*32 + lq*8..+8
  const bf16* Ab = G2 + (long)ms32*131072 + mif*128 + lq*256 + lr*8;

  f32x4 acc[4];
  #pragma unroll
  for (int ni=0; ni<4; ++ni) acc[ni] = {0.f,0.f,0.f,0.f};

  bf16x8 A[2];
  A[0] = *(const bf16x8*)(Ab + (long)kc0*1024);

  for (int jj = 0; jj < 8; ++jj) {
    STEPG(0, 1, 2*jj);
    STEPG(1, 0, 2*jj + 1);
  }

  if (s == 0) {                                   // fold +32*b2[h] (out zeroed)
    #pragma unroll
    for (int ni=0; ni<4; ++ni) {
      float bv = 32.0f * b2[csx*64 + ni*16 + lr];
      #pragma unroll
      for (int r=0; r<4; ++r) acc[ni][r] += bv;
    }
  }

  #pragma unroll
  for (int ni=0; ni<4; ++ni) {
    int h = csx*64 + ni*16 + lr;
    #pragma unroll
    for (int r=0; r<4; ++r) {
      int b = ms16*16 + lq*4 + r;
      atomicAdd(&out[b*256 + 128 + h], acc[ni][r]);
    }
  }
}

// ---------------- launch ----------------
extern "C" void kernel_launch(void* const* d_in, const int* in_sizes, int n_in,
                              void* d_out, int out_size, void* d_ws, size_t ws_size,
                              hipStream_t stream) {
  const float* in = (const float*)d_in[0];
  const float* W1 = (const float*)d_in[1];
  const float* b1 = (const float*)d_in[2];
  const float* W2 = (const float*)d_in[3];
  const float* b2 = (const float*)d_in[4];
  float* out = (float*)d_out;

  char* ws = (char*)d_ws;
  bf16* w1t  = (bf16*)(ws);                 // 2*27*2048*2  = 221,184
  bf16* w2t2 = (bf16*)(ws + 1048576);       // 2*130*2048*2 = 1,064,960
  bf16* G2   = (bf16*)(ws + 4194304);       // 2048*4096*2  = 16,777,216 (end ~21 MB)

  prep_all<<<628, 256, 0, stream>>>(W1, W2, w1t, w2t2);
  cin1G  <<<512, 256, 0, stream>>>(in, w1t, b1, G2, out);
  gemm2  <<<512, 256, 0, stream>>>(G2, w2t2, b2, out);
}

// Round 11
// 95.190 us; speedup vs baseline: 1.3861x; 1.0717x over previous
//
#include <hip/hip_runtime.h>

typedef __bf16 bf16;
typedef __bf16 bf16x8 __attribute__((ext_vector_type(8)));
typedef __bf16 bf16x4 __attribute__((ext_vector_type(4)));
typedef float f32x4 __attribute__((ext_vector_type(4)));
typedef unsigned int u32;

#define NB    2048
#define NM    26
#define NJP   27      // 26 K-chunks + 1 zero pad (unconditional prefetch)

// ---------------- prep: frag-linear weight tiles (w1t + w2t2) ----------------
// In a 64x32 tile, element (r=ni*16+lr, c=lq*8+el) lives at
// ni*512 + lq*128 + lr*8 + el.  643,072 elems = 628 blocks * 256 * 4 exactly.
__global__ __launch_bounds__(256) void prep_all(
    const float* __restrict__ W1, const float* __restrict__ W2,
    bf16* __restrict__ w1t, bf16* __restrict__ w2t2)
{
  const int bid = blockIdx.x, t = threadIdx.x;
  #pragma unroll
  for (int g = 0; g < 4; ++g) {
    int ge = g*160768 + bid*256 + t;
    if (ge < 110592) {                    // w1t tiles [cs(2)][c(NJP)], frag-linear
      int e = ge;
      int el = e & 7, lr = (e >> 3) & 15, lq = (e >> 7) & 3, ni = (e >> 9) & 3;
      int rest = e >> 11;
      int c = rest % NJP, cs_idx = rest / NJP;
      int h = cs_idx*64 + ni*16 + lr;
      int i = lq*8 + el;
      float v = (i < NM && c < NM) ? W1[h*(NM*NM) + i*NM + c] : 0.f;
      w1t[e] = (bf16)v;
    } else {                              // w2t2 tiles [cs2(2)][kc(130)], frag-linear
      int e = ge - 110592;                // flatK = kc*32 + c  (kc=i, c=j)
      int el = e & 7, lr = (e >> 3) & 15, lq = (e >> 7) & 3, ni = (e >> 9) & 3;
      int rest = e >> 11;                 // [0, 260)
      int kc = rest % 130, cs_idx = rest / 130;
      int h = cs_idx*64 + ni*16 + lr;
      int c = lq*8 + el;
      float v = (kc < 128 && c < NM) ? W2[h*(128*NM) + kc*NM + c] : 0.f;
      w2t2[e] = (bf16)v;
    }
  }
}

// layer-1 K-chunk step: scalars (f32) + B-frags prefetched 1 ahead; compute
// chunk J for BOTH batches from buffer CUR. af built in f32 then converted.
#define STEP(CUR, NXT, J) do {                                                 \
  { int jn = ((J)+1 > 25) ? 25 : (J)+1;  /* chunk-26 weights are zero */       \
    scf[NXT][0][0] = spw0[jn*32];  scf[NXT][0][1] = spw0[jn*32 + 16];          \
    scf[NXT][1][0] = spw1[jn*32];  scf[NXT][1][1] = spw1[jn*32 + 16]; }        \
  _Pragma("unroll")                                                            \
  for (int ni = 0; ni < 4; ++ni)                                               \
    B[NXT][ni] = *(const bf16x8*)(tb + (long)((J)+1)*2048 + ni*512);           \
  _Pragma("unroll")                                                            \
  for (int bb = 0; bb < 2; ++bb)                                               \
    _Pragma("unroll")                                                          \
    for (int mi = 0; mi < 2; ++mi) {                                           \
      bf16x8 af;                                                               \
      _Pragma("unroll")                                                        \
      for (int e = 0; e < 8; ++e)                                              \
        af[e] = (bf16)(xf32[bb][mi][e] * scf[CUR][bb][mi]);                    \
      _Pragma("unroll")                                                        \
      for (int ni = 0; ni < 4; ++ni)                                           \
        acc[bb][mi][ni] = __builtin_amdgcn_mfma_f32_16x16x32_bf16(af,          \
                                    B[CUR][ni], acc[bb][mi][ni], 0, 0, 0);     \
    }                                                                          \
} while (0)

// mini-gemm K-step: A (LDS G-tile) + 2 B-frags (w2t2, L2) prefetched 1 ahead.
// KL+1 prefetch at KL=63 reads ldsG pad slots / w2t2 zero rows (harmless,
// in-bounds: ldsG padded to 264 slots, w2t2 has 130 kc rows).
#define STEPM(CUR, NXT, KL) do {                                               \
  Af[NXT] = *(const bf16x8*)&ldsG[(((KL)+1)*4 + lq)*72 + lr*8];                \
  Bf[NXT][0] = *(const bf16x8*)(Bb0 + (long)((KL)+1)*2048);                    \
  Bf[NXT][1] = *(const bf16x8*)(Bb1 + (long)((KL)+1)*2048);                    \
  _Pragma("unroll")                                                            \
  for (int ht = 0; ht < 2; ++ht)                                               \
    acc2[ht] = __builtin_amdgcn_mfma_f32_16x16x32_bf16(Af[CUR], Bf[CUR][ht],   \
                                                       acc2[ht], 0, 0, 0);     \
} while (0)

// ---------------- fused: layer 1 + G (LDS) + layer-2 mini-gemm ---------------
// Block = 8 batches x one cs-half (i in [cs,cs+64)). Waves own 2 batches each.
// Layer 1 + swapped G-MFMA as in r8, but G goes to a padded LDS A-tile
// ldsG[k8(256 used + 8 pad slots)][b(8)][8] (slot stride 72 elems). One
// barrier, then each wave computes out2[8b x 32h] over K=2048 (this cs-half):
// A from ldsG, B reg-dbuf from w2t2 (kc = cs..cs+64).
// Atomics: 8b x 128h per block; cs==0 blocks fold +32*b2[h] (out zeroed).
// MFMA C-rows are independent: garbage A-rows 8..15 (lanes lr>=8 read
// neighboring slots) only affect discarded C-rows 8..15.
__global__ __launch_bounds__(256, 2) void cinfuse(
    const float* __restrict__ in, const bf16* __restrict__ w1t,
    const bf16* __restrict__ w2t2, const float* __restrict__ b1,
    const float* __restrict__ b2, float* __restrict__ out)
{
  __shared__ __align__(16) bf16 ldsT[4][64*36];   // 18,432 B (wave-private x1^T)
  __shared__ __align__(16) bf16 ldsG[264*72];     // 38,016 B (G A-tile, padded)
  const int t = threadIdx.x, bid = blockIdx.x;
  const int lane = t & 63, w = t >> 6;
  const int lr = lane & 15, lq = lane >> 4;
  const int fo = lq*128 + lr*8;
  const int cs_idx = bid & 1, cs = cs_idx * 64;
  const int grp = bid >> 1;                       // 0..255, 8 batches each
  const int bw0 = grp*8 + w*2;                    // this wave's batches bw0, bw0+1

  const float* bin0 = in + (long)bw0*(NM*32);
  const float* bin1 = bin0 + NM*32;
  const float* spw0 = bin0 + lr;                  // + j*32 + mi*16 (k = mi*16+lr)
  const float* spw1 = bin1 + lr;

  // x0 A-frags in f32: xf32[bb][mi][e] = x0[bw0+bb][j=lq*8+e][k=mi*16+lr]
  float xf32[2][2][8];
  #pragma unroll
  for (int bb = 0; bb < 2; ++bb) {
    const float* bin = bb ? bin1 : bin0;
    #pragma unroll
    for (int mi = 0; mi < 2; ++mi)
      #pragma unroll
      for (int e = 0; e < 8; ++e) {
        int j = lq*8 + e;
        xf32[bb][mi][e] = (j < NM) ? bin[j*32 + mi*16 + lr] : 0.f;
      }
  }

  f32x4 acc[2][2][4];
  #pragma unroll
  for (int bb=0; bb<2; ++bb)
    #pragma unroll
    for (int mi=0; mi<2; ++mi)
      #pragma unroll
      for (int ni=0; ni<4; ++ni) acc[bb][mi][ni] = {0.f,0.f,0.f,0.f};

  const bf16* tb = w1t + (long)cs_idx*NJP*2048 + fo;

  float scf[2][2][2];
  bf16x8 B[2][4];
  #pragma unroll
  for (int ni = 0; ni < 4; ++ni)
    B[0][ni] = *(const bf16x8*)(tb + ni*512);     // chunk 0
  scf[0][0][0] = spw0[0];  scf[0][0][1] = spw0[16];
  scf[0][1][0] = spw1[0];  scf[0][1][1] = spw1[16];

  for (int jj = 0; jj < 13; ++jj) {
    STEP(0, 1, 2*jj);
    STEP(1, 0, 2*jj + 1);
  }

  float bias[4];
  #pragma unroll
  for (int ni=0; ni<4; ++ni) bias[ni] = b1[cs + ni*16 + lr];

  bf16* T = &ldsT[w][0];

  #pragma unroll
  for (int bb = 0; bb < 2; ++bb) {
    const int bw = bw0 + bb;
    const int bloc = w*2 + bb;                    // block-local batch 0..7
    const float* bin = bb ? bin1 : bin0;

    // out[bw][cs:cs+64] = k-sum of x1 + 32*bias
    #pragma unroll
    for (int ni=0; ni<4; ++ni) {
      float vv = 0.f;
      #pragma unroll
      for (int mi=0; mi<2; ++mi)
        #pragma unroll
        for (int r=0; r<4; ++r) vv += acc[bb][mi][ni][r];
      vv += __shfl_xor(vv, 16, 64);
      vv += __shfl_xor(vv, 32, 64);
      if (lq == 0) out[bw*256 + cs + ni*16 + lr] = vv + 32.0f * bias[ni];
    }

    // x1 (C-layout) -> wave-private LDS [i_local][k], row stride 36
    #pragma unroll
    for (int mi=0; mi<2; ++mi)
      #pragma unroll
      for (int ni=0; ni<4; ++ni) {
        bf16x4 pk;
        #pragma unroll
        for (int r=0; r<4; ++r) pk[r] = (bf16)(acc[bb][mi][ni][r] + bias[ni]);
        *(bf16x4*)&T[(ni*16+lr)*36 + mi*16 + lq*4] = pk;
      }
    // no barrier: wave-private tile; same-wave DS ordering protects reuse

    // B-frags: x0[j][k] from in
    bf16x8 bg[2];
    #pragma unroll
    for (int nt = 0; nt < 2; ++nt) {
      int j = nt*16 + lr;
      bf16x8 vv;
      #pragma unroll
      for (int e=0; e<8; ++e) vv[e] = (bf16)0.f;
      if (j < NM) {
        const float* src = bin + j*32 + lq*8;
        f32x4 a = *(const f32x4*)src, c = *(const f32x4*)(src+4);
        #pragma unroll
        for (int e=0; e<4; ++e) { vv[e] = (bf16)a[e]; vv[4+e] = (bf16)c[e]; }
      }
      bg[nt] = vv;
    }
    // swapped G-MFMAs; G goes to the LDS A-tile (local i, padded slots)
    #pragma unroll
    for (int mt = 0; mt < 4; ++mt) {
      bf16x8 ag = *(const bf16x8*)&T[(mt*16+lr)*36 + lq*8];
      #pragma unroll
      for (int nt = 0; nt < 2; ++nt) {
        f32x4 z = {0.f,0.f,0.f,0.f};
        f32x4 g = __builtin_amdgcn_mfma_f32_16x16x32_bf16(bg[nt], ag, z, 0, 0, 0);
        // lane holds G[bw][i_loc=mt*16+lr][j=nt*16+lq*4+r]
        bf16x4 pk;
        #pragma unroll
        for (int r = 0; r < 4; ++r) pk[r] = (bf16)g[r];
        const int kh = (mt*16 + lr)*4 + nt*2 + (lq >> 1);   // flatK_loc >> 3
        *(bf16x4*)&ldsG[kh*72 + bloc*8 + (lq & 1)*4] = pk;
      }
    }
  }

  __syncthreads();                                // all 8 batches' G in ldsG

  // ---- mini-gemm: wave w owns h-tiles {w*2, w*2+1} ----
  const int ht0 = w*2, ht1 = w*2 + 1;
  const bf16* Bb0 = w2t2 + ((long)(ht0 >> 2)*130 + cs)*2048 + (ht0 & 3)*512 + fo;
  const bf16* Bb1 = w2t2 + ((long)(ht1 >> 2)*130 + cs)*2048 + (ht1 & 3)*512 + fo;

  f32x4 acc2[2];
  acc2[0] = {0.f,0.f,0.f,0.f};  acc2[1] = {0.f,0.f,0.f,0.f};

  bf16x8 Af[2], Bf[2][2];
  Af[0] = *(const bf16x8*)&ldsG[lq*72 + lr*8];    // kc_loc = 0
  Bf[0][0] = *(const bf16x8*)Bb0;
  Bf[0][1] = *(const bf16x8*)Bb1;

  for (int jj = 0; jj < 32; ++jj) {
    STEPM(0, 1, 2*jj);
    STEPM(1, 0, 2*jj + 1);
  }

  if (cs_idx == 0) {                              // fold +32*b2[h] once
    #pragma unroll
    for (int ht = 0; ht < 2; ++ht) {
      float bv = 32.0f * b2[(w*2 + ht)*16 + lr];
      #pragma unroll
      for (int r=0; r<4; ++r) acc2[ht][r] += bv;
    }
  }

  // C-layout: col(lr)=h within tile, row(lq*4+r)=b_loc (valid rows < 8)
  if (lq < 2) {
    #pragma unroll
    for (int ht = 0; ht < 2; ++ht) {
      int h = (w*2 + ht)*16 + lr;
      #pragma unroll
      for (int r=0; r<4; ++r) {
        int b = grp*8 + lq*4 + r;
        atomicAdd(&out[b*256 + 128 + h], acc2[ht][r]);
      }
    }
  }
}

// ---------------- launch ----------------
extern "C" void kernel_launch(void* const* d_in, const int* in_sizes, int n_in,
                              void* d_out, int out_size, void* d_ws, size_t ws_size,
                              hipStream_t stream) {
  const float* in = (const float*)d_in[0];
  const float* W1 = (const float*)d_in[1];
  const float* b1 = (const float*)d_in[2];
  const float* W2 = (const float*)d_in[3];
  const float* b2 = (const float*)d_in[4];
  float* out = (float*)d_out;

  char* ws = (char*)d_ws;
  bf16* w1t  = (bf16*)(ws);                 // 2*27*2048*2  = 221,184
  bf16* w2t2 = (bf16*)(ws + 1048576);       // 2*130*2048*2 = 1,064,960

  prep_all<<<628, 256, 0, stream>>>(W1, W2, w1t, w2t2);
  cinfuse <<<512, 256, 0, stream>>>(in, w1t, w2t2, b1, b2, out);
}

// Round 12
// 91.900 us; speedup vs baseline: 1.4357x; 1.0358x over previous
//
#include <hip/hip_runtime.h>

typedef __bf16 bf16;
typedef __bf16 bf16x8 __attribute__((ext_vector_type(8)));
typedef __bf16 bf16x4 __attribute__((ext_vector_type(4)));
typedef float f32x4 __attribute__((ext_vector_type(4)));
typedef unsigned int u32;

#define NB    2048
#define NM    26
#define NJP   27      // 26 K-chunks + 1 zero pad (unconditional prefetch)

// ---------------- prep: frag-linear weight tiles (w1t + w2t2) ----------------
// In a 64x32 tile, element (r=ni*16+lr, c=lq*8+el) lives at
// ni*512 + lq*128 + lr*8 + el.  643,072 elems = 628 blocks * 256 * 4 exactly.
__global__ __launch_bounds__(256) void prep_all(
    const float* __restrict__ W1, const float* __restrict__ W2,
    bf16* __restrict__ w1t, bf16* __restrict__ w2t2)
{
  const int bid = blockIdx.x, t = threadIdx.x;
  #pragma unroll
  for (int g = 0; g < 4; ++g) {
    int ge = g*160768 + bid*256 + t;
    if (ge < 110592) {                    // w1t tiles [cs(2)][c(NJP)], frag-linear
      int e = ge;
      int el = e & 7, lr = (e >> 3) & 15, lq = (e >> 7) & 3, ni = (e >> 9) & 3;
      int rest = e >> 11;
      int c = rest % NJP, cs_idx = rest / NJP;
      int h = cs_idx*64 + ni*16 + lr;
      int i = lq*8 + el;
      float v = (i < NM && c < NM) ? W1[h*(NM*NM) + i*NM + c] : 0.f;
      w1t[e] = (bf16)v;
    } else {                              // w2t2 tiles [cs2(2)][kc(130)], frag-linear
      int e = ge - 110592;                // flatK = kc*32 + c  (kc=i, c=j)
      int el = e & 7, lr = (e >> 3) & 15, lq = (e >> 7) & 3, ni = (e >> 9) & 3;
      int rest = e >> 11;                 // [0, 260)
      int kc = rest % 130, cs_idx = rest / 130;
      int h = cs_idx*64 + ni*16 + lr;
      int c = lq*8 + el;
      float v = (kc < 128 && c < NM) ? W2[h*(128*NM) + kc*NM + c] : 0.f;
      w2t2[e] = (bf16)v;
    }
  }
}

// layer-1 K-chunk step: scalars (f32) + B-frags prefetched 1 ahead; compute
// chunk J for BOTH batches from buffer CUR. af built in f32 then converted.
#define STEP(CUR, NXT, J) do {                                                 \
  { int jn = ((J)+1 > 25) ? 25 : (J)+1;  /* chunk-26 weights are zero */       \
    scf[NXT][0][0] = spw0[jn*32];  scf[NXT][0][1] = spw0[jn*32 + 16];          \
    scf[NXT][1][0] = spw1[jn*32];  scf[NXT][1][1] = spw1[jn*32 + 16]; }        \
  _Pragma("unroll")                                                            \
  for (int ni = 0; ni < 4; ++ni)                                               \
    B[NXT][ni] = *(const bf16x8*)(tb + (long)((J)+1)*2048 + ni*512);           \
  _Pragma("unroll")                                                            \
  for (int bb = 0; bb < 2; ++bb)                                               \
    _Pragma("unroll")                                                          \
    for (int mi = 0; mi < 2; ++mi) {                                           \
      bf16x8 af;                                                               \
      _Pragma("unroll")                                                        \
      for (int e = 0; e < 8; ++e)                                              \
        af[e] = (bf16)(xf32[bb][mi][e] * scf[CUR][bb][mi]);                    \
      _Pragma("unroll")                                                        \
      for (int ni = 0; ni < 4; ++ni)                                           \
        acc[bb][mi][ni] = __builtin_amdgcn_mfma_f32_16x16x32_bf16(af,          \
                                    B[CUR][ni], acc[bb][mi][ni], 0, 0, 0);     \
    }                                                                          \
} while (0)

// mini-gemm K-step: A (LDS, 2-deep ping-pong) + B (w2t2 L2, 4-deep cyclic).
// CA/NA and Q are LITERALS -> all register indices compile-time (no scratch).
// Tail prefetches (KL+1=64 -> ldsU pad slots; KL+3<=66 -> past w2t2 into
// mapped workspace gap) are never consumed.
#define STEPM(CA, NA, KL, Q) do {                                              \
  Af[NA] = *(const bf16x8*)&ldsU[(((KL)+1)*4 + lq)*72 + lr*8];                 \
  Bf[((Q)+3)&3][0] = *(const bf16x8*)(Bb0 + (long)((KL)+3)*2048);              \
  Bf[((Q)+3)&3][1] = *(const bf16x8*)(Bb1 + (long)((KL)+3)*2048);              \
  _Pragma("unroll")                                                            \
  for (int ht = 0; ht < 2; ++ht)                                               \
    acc2[ht] = __builtin_amdgcn_mfma_f32_16x16x32_bf16(Af[CA], Bf[(Q)][ht],    \
                                                       acc2[ht], 0, 0, 0);     \
} while (0)

// ---------------- fused: layer 1 + G (LDS) + layer-2 mini-gemm ---------------
// Block = 8 batches x one cs-half. LDS is a 38 KB UNION with two lifetimes:
// phase A = 4 wave-private x1^T tiles (9,216 elems used), phase B = padded
// G A-tile ldsG[k8(256+8 pad)][b(8)][8] (slot stride 72). Phases separated
// by a barrier (ag/bg held in registers across it). 3 blocks/CU.
// Mini-gemm: out2[8b x 32h] over K=2048, A from LDS, B 4-deep from w2t2.
__global__ __launch_bounds__(256, 3) void cinfuse(
    const float* __restrict__ in, const bf16* __restrict__ w1t,
    const bf16* __restrict__ w2t2, const float* __restrict__ b1,
    const float* __restrict__ b2, float* __restrict__ out)
{
  __shared__ __align__(16) bf16 ldsU[264*72];     // 38,016 B (union, see above)
  const int t = threadIdx.x, bid = blockIdx.x;
  const int lane = t & 63, w = t >> 6;
  const int lr = lane & 15, lq = lane >> 4;
  const int fo = lq*128 + lr*8;
  const int cs_idx = bid & 1, cs = cs_idx * 64;
  const int grp = bid >> 1;                       // 0..255, 8 batches each
  const int bw0 = grp*8 + w*2;                    // this wave's batches bw0, bw0+1

  const float* bin0 = in + (long)bw0*(NM*32);
  const float* bin1 = bin0 + NM*32;
  const float* spw0 = bin0 + lr;                  // + j*32 + mi*16 (k = mi*16+lr)
  const float* spw1 = bin1 + lr;

  // x0 A-frags in f32: xf32[bb][mi][e] = x0[bw0+bb][j=lq*8+e][k=mi*16+lr]
  float xf32[2][2][8];
  #pragma unroll
  for (int bb = 0; bb < 2; ++bb) {
    const float* bin = bb ? bin1 : bin0;
    #pragma unroll
    for (int mi = 0; mi < 2; ++mi)
      #pragma unroll
      for (int e = 0; e < 8; ++e) {
        int j = lq*8 + e;
        xf32[bb][mi][e] = (j < NM) ? bin[j*32 + mi*16 + lr] : 0.f;
      }
  }

  f32x4 acc[2][2][4];
  #pragma unroll
  for (int bb=0; bb<2; ++bb)
    #pragma unroll
    for (int mi=0; mi<2; ++mi)
      #pragma unroll
      for (int ni=0; ni<4; ++ni) acc[bb][mi][ni] = {0.f,0.f,0.f,0.f};

  const bf16* tb = w1t + (long)cs_idx*NJP*2048 + fo;

  float scf[2][2][2];
  bf16x8 B[2][4];
  #pragma unroll
  for (int ni = 0; ni < 4; ++ni)
    B[0][ni] = *(const bf16x8*)(tb + ni*512);     // chunk 0
  scf[0][0][0] = spw0[0];  scf[0][0][1] = spw0[16];
  scf[0][1][0] = spw1[0];  scf[0][1][1] = spw1[16];

  for (int jj = 0; jj < 13; ++jj) {
    STEP(0, 1, 2*jj);
    STEP(1, 0, 2*jj + 1);
  }

  float bias[4];
  #pragma unroll
  for (int ni=0; ni<4; ++ni) bias[ni] = b1[cs + ni*16 + lr];

  bf16* T = &ldsU[w*2304];                        // wave-private x1^T [64][36]

  bf16x8 agr[2][4];                               // held across the barrier
  bf16x8 bgr[2][2];

  #pragma unroll
  for (int bb = 0; bb < 2; ++bb) {
    const int bw = bw0 + bb;
    const float* bin = bb ? bin1 : bin0;

    // out[bw][cs:cs+64] = k-sum of x1 + 32*bias
    #pragma unroll
    for (int ni=0; ni<4; ++ni) {
      float vv = 0.f;
      #pragma unroll
      for (int mi=0; mi<2; ++mi)
        #pragma unroll
        for (int r=0; r<4; ++r) vv += acc[bb][mi][ni][r];
      vv += __shfl_xor(vv, 16, 64);
      vv += __shfl_xor(vv, 32, 64);
      if (lq == 0) out[bw*256 + cs + ni*16 + lr] = vv + 32.0f * bias[ni];
    }

    // x1 (C-layout) -> wave-private x1^T tile [i_local][k], row stride 36
    #pragma unroll
    for (int mi=0; mi<2; ++mi)
      #pragma unroll
      for (int ni=0; ni<4; ++ni) {
        bf16x4 pk;
        #pragma unroll
        for (int r=0; r<4; ++r) pk[r] = (bf16)(acc[bb][mi][ni][r] + bias[ni]);
        *(bf16x4*)&T[(ni*16+lr)*36 + mi*16 + lq*4] = pk;
      }
    // same-wave DS ordering: reads below see this wave's writes

    // A-frags of x1^T -> registers (survive the LDS repurposing barrier)
    #pragma unroll
    for (int mt = 0; mt < 4; ++mt)
      agr[bb][mt] = *(const bf16x8*)&T[(mt*16+lr)*36 + lq*8];

    // B-frags: x0[j][k] from in -> registers
    #pragma unroll
    for (int nt = 0; nt < 2; ++nt) {
      int j = nt*16 + lr;
      bf16x8 vv;
      #pragma unroll
      for (int e=0; e<8; ++e) vv[e] = (bf16)0.f;
      if (j < NM) {
        const float* src = bin + j*32 + lq*8;
        f32x4 a = *(const f32x4*)src, c = *(const f32x4*)(src+4);
        #pragma unroll
        for (int e=0; e<4; ++e) { vv[e] = (bf16)a[e]; vv[4+e] = (bf16)c[e]; }
      }
      bgr[bb][nt] = vv;
    }
  }

  __syncthreads();            // all x1^T reads done -> ldsU becomes the G-tile

  // swapped G-MFMAs; G goes to the LDS A-tile (local i, padded slots)
  #pragma unroll
  for (int bb = 0; bb < 2; ++bb) {
    const int bloc = w*2 + bb;                    // block-local batch 0..7
    #pragma unroll
    for (int mt = 0; mt < 4; ++mt) {
      #pragma unroll
      for (int nt = 0; nt < 2; ++nt) {
        f32x4 z = {0.f,0.f,0.f,0.f};
        f32x4 g = __builtin_amdgcn_mfma_f32_16x16x32_bf16(bgr[bb][nt],
                                                          agr[bb][mt], z, 0, 0, 0);
        // lane holds G[bw][i_loc=mt*16+lr][j=nt*16+lq*4+r]
        bf16x4 pk;
        #pragma unroll
        for (int r = 0; r < 4; ++r) pk[r] = (bf16)g[r];
        const int kh = (mt*16 + lr)*4 + nt*2 + (lq >> 1);   // flatK_loc >> 3
        *(bf16x4*)&ldsU[kh*72 + bloc*8 + (lq & 1)*4] = pk;
      }
    }
  }

  __syncthreads();                                // all 8 batches' G in ldsU

  // ---- mini-gemm: wave w owns h-tiles {w*2, w*2+1} ----
  const int ht0 = w*2, ht1 = w*2 + 1;
  const bf16* Bb0 = w2t2 + ((long)(ht0 >> 2)*130 + cs)*2048 + (ht0 & 3)*512 + fo;
  const bf16* Bb1 = w2t2 + ((long)(ht1 >> 2)*130 + cs)*2048 + (ht1 & 3)*512 + fo;

  f32x4 acc2[2];
  acc2[0] = {0.f,0.f,0.f,0.f};  acc2[1] = {0.f,0.f,0.f,0.f};

  bf16x8 Af[2], Bf[4][2];
  Af[0] = *(const bf16x8*)&ldsU[lq*72 + lr*8];    // kc_loc = 0
  #pragma unroll
  for (int d = 0; d < 3; ++d) {
    Bf[d][0] = *(const bf16x8*)(Bb0 + (long)d*2048);
    Bf[d][1] = *(const bf16x8*)(Bb1 + (long)d*2048);
  }

  for (int jj = 0; jj < 16; ++jj) {
    const int KL0 = jj*4;
    STEPM(0, 1, KL0+0, 0);
    STEPM(1, 0, KL0+1, 1);
    STEPM(0, 1, KL0+2, 2);
    STEPM(1, 0, KL0+3, 3);
  }

  if (cs_idx == 0) {                              // fold +32*b2[h] once
    #pragma unroll
    for (int ht = 0; ht < 2; ++ht) {
      float bv = 32.0f * b2[(w*2 + ht)*16 + lr];
      #pragma unroll
      for (int r=0; r<4; ++r) acc2[ht][r] += bv;
    }
  }

  // C-layout: col(lr)=h within tile, row(lq*4+r)=b_loc (valid rows < 8)
  if (lq < 2) {
    #pragma unroll
    for (int ht = 0; ht < 2; ++ht) {
      int h = (w*2 + ht)*16 + lr;
      #pragma unroll
      for (int r=0; r<4; ++r) {
        int b = grp*8 + lq*4 + r;
        atomicAdd(&out[b*256 + 128 + h], acc2[ht][r]);
      }
    }
  }
}

// ---------------- launch ----------------
extern "C" void kernel_launch(void* const* d_in, const int* in_sizes, int n_in,
                              void* d_out, int out_size, void* d_ws, size_t ws_size,
                              hipStream_t stream) {
  const float* in = (const float*)d_in[0];
  const float* W1 = (const float*)d_in[1];
  const float* b1 = (const float*)d_in[2];
  const float* W2 = (const float*)d_in[3];
  const float* b2 = (const float*)d_in[4];
  float* out = (float*)d_out;

  char* ws = (char*)d_ws;
  bf16* w1t  = (bf16*)(ws);                 // 2*27*2048*2  = 221,184
  bf16* w2t2 = (bf16*)(ws + 1048576);       // 2*130*2048*2 = 1,064,960

  prep_all<<<628, 256, 0, stream>>>(W1, W2, w1t, w2t2);
  cinfuse <<<512, 256, 0, stream>>>(in, w1t, w2t2, b1, b2, out);
}